// Round 13
// baseline (1632.995 us; speedup 1.0000x reference)
//
#include <hip/hip_runtime.h>

// ---------------------------------------------------------------------------
// TransformerAgent (Performer/FAVOR+ encoder), MI355X gfx950.
// Round 13: hybrid operand paths in the GEMMs — A-fragments read DIRECTLY
// from global via b128 loads (VMEM/L1 pipe), B staged in LDS. Halves LDS
// pipe pressure (the measured ~24% MfmaUtil ceiling was LDS-BW-bound:
// 64x64 wave tile needs ~845 B/cyc of LDS at full MFMA rate vs ~256 avail).
// GEMM LDS drops 48->32 KB. favorWo kernel already used this hybrid for Q.
// B=16, L=4096(=1+4095), HID=256, NH=8, DH=32, FF=1024, NL=4, ACT=32
// ---------------------------------------------------------------------------

typedef unsigned short bf16_t;
typedef __attribute__((ext_vector_type(8))) short short8;
typedef __attribute__((ext_vector_type(4))) float float4v;

#define NB 16
#define LSEQ 4096
#define MROWS (NB * LSEQ)      // 65536
#define HIDD 256
#define NHEAD 8
#define DHEAD 32
#define FFD 1024
#define NLAY 4
#define KEPS_F 1e-3f
#define LNEPS_F 1e-6f
#define KV_ELEMS (NB * NHEAD * 32 * 33)   // 135168

__device__ __forceinline__ float b2f(bf16_t h) {
    return __uint_as_float(((unsigned int)h) << 16);
}
__device__ __forceinline__ bf16_t f2b(float f) {
    unsigned int u = __float_as_uint(f);
    u += 0x7fffu + ((u >> 16) & 1u);   // round-to-nearest-even
    return (bf16_t)(u >> 16);
}

// async global->LDS, 16B per lane
#define GLOAD_LDS16(g, l)                                                     \
    __builtin_amdgcn_global_load_lds(                                         \
        (const __attribute__((address_space(1))) void*)(g),                   \
        (__attribute__((address_space(3))) void*)(l), 16, 0, 0)

// ---------------------------------------------------------------------------
// Convert+transpose: in[z*ils + R][C] f32 -> out[z*ols + C][R] bf16.
// ---------------------------------------------------------------------------
__global__ __launch_bounds__(256) void conv_transpose_kernel(
    const float* __restrict__ in, bf16_t* __restrict__ out, int R, int C,
    size_t ils, size_t ols)
{
    __shared__ float tile[32][33];
    const size_t ib = (size_t)blockIdx.z * ils;
    const size_t ob = (size_t)blockIdx.z * ols;
    const int r0 = blockIdx.y * 32, c0 = blockIdx.x * 32;
    const int tx = threadIdx.x & 31, ty = threadIdx.x >> 5;   // 32 x 8
#pragma unroll
    for (int rr = ty; rr < 32; rr += 8)
        tile[rr][tx] = in[ib + (size_t)(r0 + rr) * C + c0 + tx];
    __syncthreads();
#pragma unroll
    for (int rr = ty; rr < 32; rr += 8)
        out[ob + (size_t)(c0 + rr) * R + r0 + tx] = f2b(tile[tx][rr]);
}

// concat per-layer q/k/v biases into bqkv[l][768]
__global__ __launch_bounds__(256) void concat_bias_kernel(
    const float* __restrict__ bq, const float* __restrict__ bk,
    const float* __restrict__ bv, float* __restrict__ bqkv)
{
    const int l = blockIdx.x, j = threadIdx.x;
    bqkv[l * 768 + j]       = bq[l * 256 + j];
    bqkv[l * 768 + 256 + j] = bk[l * 256 + j];
    bqkv[l * 768 + 512 + j] = bv[l * 256 + j];
}

// ---------------------------------------------------------------------------
// Embed A-prep: Ain[b*4096+l][128] = (l==0) ? 0 : bf16(ins[b][l-1][:])
// ---------------------------------------------------------------------------
__global__ __launch_bounds__(256) void prep_a_kernel(
    const float* __restrict__ ins, bf16_t* __restrict__ Ain)
{
    const int row = blockIdx.x * 2 + (threadIdx.x >> 7);
    const int j = threadIdx.x & 127;
    const int b = row >> 12, l = row & (LSEQ - 1);
    bf16_t v = 0;
    if (l != 0) v = f2b(ins[((size_t)b * 4095 + (l - 1)) * 128 + j]);
    Ain[(size_t)row * 128 + j] = v;
}

// X[b,0,:] = resets ? 0 : hidden
__global__ __launch_bounds__(256) void fix_row0_kernel(
    const float* __restrict__ hidden, const int* __restrict__ resets,
    bf16_t* __restrict__ X)
{
    const int b = blockIdx.x, j = threadIdx.x;
    float v = resets[b] ? 0.f : hidden[b * HIDD + j];
    X[((size_t)b * LSEQ) * HIDD + j] = f2b(v);
}

// ---------------------------------------------------------------------------
// MFMA GEMM (plain, hybrid): C = act(A @ W + bias); WT[N][K]. 512 thr =
// 8 waves, block 128x256, wave 64x64 (2m x 4n). A-frags: direct global b128
// (16 full 64-B lines per instr; L1-resident per k0). B: LDS, XOR-swizzled.
// ---------------------------------------------------------------------------
template <int MODE>
__global__ __launch_bounds__(512) void gemm_mfma(
    const bf16_t* __restrict__ A, const bf16_t* __restrict__ WT,
    const float* __restrict__ bias, bf16_t* __restrict__ C,
    int M, int N, int K, int lda, int ldc)
{
    __shared__ __align__(16) bf16_t Bs[256 * 64];   // 32 KB
    const int tid = threadIdx.x;
    const int wave = tid >> 6, lane = tid & 63;
    const int bm = blockIdx.y * 128, bn = blockIdx.x * 256;
    const int quad = lane >> 4, mr = lane & 15;
    const int mxor = mr & 7;
    const int wm0 = (wave & 1) * 64;       // m-half
    const int wn0 = (wave >> 1) * 64;      // n-quarter

    const bf16_t* Arow[4];
#pragma unroll
    for (int i = 0; i < 4; i++)
        Arow[i] = A + (size_t)(bm + wm0 + i * 16 + mr) * lda + quad * 8;

    float4v acc[4][4];
#pragma unroll
    for (int i = 0; i < 4; i++)
#pragma unroll
        for (int j = 0; j < 4; j++) acc[i][j] = (float4v)(0.f);

    for (int k0 = 0; k0 < K; k0 += 64) {
        // A-frags direct from global (VMEM pipe, issued before the barrier)
        short8 a0[4], a1[4];
#pragma unroll
        for (int i = 0; i < 4; i++) {
            a0[i] = *(const short8*)(Arow[i] + k0);
            a1[i] = *(const short8*)(Arow[i] + k0 + 32);
        }
        // B staged to LDS (async)
#pragma unroll
        for (int it = 0; it < 4; it++) {
            const int c = it * 512 + tid;
            const int r = c >> 3;
            const int kofs = ((c & 7) ^ (r & 7)) * 8;
            GLOAD_LDS16(WT + (size_t)(bn + r) * K + k0 + kofs, &Bs[c * 8]);
        }
        __syncthreads();
#pragma unroll
        for (int kk = 0; kk < 8; kk += 4) {
            short8 b[4];
#pragma unroll
            for (int j = 0; j < 4; j++)
                b[j] = *(const short8*)&Bs[((wn0 + j * 16 + mr) * 8 + ((quad + kk) ^ mxor)) * 8];
#pragma unroll
            for (int i = 0; i < 4; i++) {
                const short8 av = (kk == 0) ? a0[i] : a1[i];
#pragma unroll
                for (int j = 0; j < 4; j++)
                    acc[i][j] = __builtin_amdgcn_mfma_f32_16x16x32_bf16(
                        av, b[j], acc[i][j], 0, 0, 0);
            }
        }
        __syncthreads();
    }

    float bcol[4];
#pragma unroll
    for (int j = 0; j < 4; j++) bcol[j] = bias[bn + wn0 + j * 16 + mr];
#pragma unroll
    for (int i = 0; i < 4; i++) {
#pragma unroll
        for (int r = 0; r < 4; r++) {
            const int grow = bm + wm0 + i * 16 + quad * 4 + r;
            bf16_t* crow = C + (size_t)grow * ldc + bn + wn0 + mr;
#pragma unroll
            for (int j = 0; j < 4; j++) {
                float v = acc[i][j][r] + bcol[j];
                if (MODE == 1) v = fmaxf(v, 0.f);
                crow[j * 16] = f2b(v);
            }
        }
    }
}

// ---------------------------------------------------------------------------
// MFMA GEMM + fused LayerNorm epilogue (hybrid A-path).
// out = LN(2*(A@W + bias)) * sc + bi. N=256; 512 thr = 8 waves (2m x 4n).
// ---------------------------------------------------------------------------
__global__ __launch_bounds__(512) void gemm_ln_mfma(
    const bf16_t* __restrict__ A, const bf16_t* __restrict__ WT,
    const float* __restrict__ bias, const float* __restrict__ sc,
    const float* __restrict__ bi, bf16_t* __restrict__ out,
    int K, int lda)
{
    __shared__ __align__(16) bf16_t Bs[256 * 64];   // 32 KB
    __shared__ float red[8][64][2];                 // 4 KB
    __shared__ float fin[128][2];                   // 1 KB

    const int tid = threadIdx.x;
    const int wave = tid >> 6, lane = tid & 63;
    const int bm = blockIdx.x * 128;
    const int quad = lane >> 4, mr = lane & 15;
    const int mxor = mr & 7;
    const int wm0 = (wave & 1) * 64;       // m-half
    const int wn0 = (wave >> 1) * 64;      // n-quarter

    const bf16_t* Arow[4];
#pragma unroll
    for (int i = 0; i < 4; i++)
        Arow[i] = A + (size_t)(bm + wm0 + i * 16 + mr) * lda + quad * 8;

    float4v acc[4][4];
#pragma unroll
    for (int i = 0; i < 4; i++)
#pragma unroll
        for (int j = 0; j < 4; j++) acc[i][j] = (float4v)(0.f);

    for (int k0 = 0; k0 < K; k0 += 64) {
        short8 a0[4], a1[4];
#pragma unroll
        for (int i = 0; i < 4; i++) {
            a0[i] = *(const short8*)(Arow[i] + k0);
            a1[i] = *(const short8*)(Arow[i] + k0 + 32);
        }
#pragma unroll
        for (int it = 0; it < 4; it++) {
            const int c = it * 512 + tid;
            const int r = c >> 3;
            const int kofs = ((c & 7) ^ (r & 7)) * 8;
            GLOAD_LDS16(WT + (size_t)r * K + k0 + kofs, &Bs[c * 8]);
        }
        __syncthreads();
#pragma unroll
        for (int kk = 0; kk < 8; kk += 4) {
            short8 b[4];
#pragma unroll
            for (int j = 0; j < 4; j++)
                b[j] = *(const short8*)&Bs[((wn0 + j * 16 + mr) * 8 + ((quad + kk) ^ mxor)) * 8];
#pragma unroll
            for (int i = 0; i < 4; i++) {
                const short8 av = (kk == 0) ? a0[i] : a1[i];
#pragma unroll
                for (int j = 0; j < 4; j++)
                    acc[i][j] = __builtin_amdgcn_mfma_f32_16x16x32_bf16(
                        av, b[j], acc[i][j], 0, 0, 0);
            }
        }
        __syncthreads();
    }

    float bcol[4];
#pragma unroll
    for (int j = 0; j < 4; j++) bcol[j] = bias[wn0 + j * 16 + mr];

#pragma unroll
    for (int i = 0; i < 4; i++) {
#pragma unroll
        for (int r = 0; r < 4; r++) {
            float s = 0.f, s2 = 0.f;
#pragma unroll
            for (int j = 0; j < 4; j++) {
                const float v = 2.0f * (acc[i][j][r] + bcol[j]);
                s += v; s2 += v * v;
            }
#pragma unroll
            for (int off = 1; off < 16; off <<= 1) {
                s  += __shfl_xor(s, off, 64);
                s2 += __shfl_xor(s2, off, 64);
            }
            if (mr == 0) {
                const int rl = i * 16 + quad * 4 + r;
                red[wave][rl][0] = s;
                red[wave][rl][1] = s2;
            }
        }
    }
    __syncthreads();
    if (tid < 256) {
        const int R = tid >> 1, p = tid & 1;
        const int mh = R >> 6, rl = R & 63;
        fin[R][p] = red[mh][rl][p] + red[mh + 2][rl][p]
                  + red[mh + 4][rl][p] + red[mh + 6][rl][p];
    }
    __syncthreads();

    float scv[4], biv[4];
#pragma unroll
    for (int j = 0; j < 4; j++) {
        scv[j] = sc[wn0 + j * 16 + mr];
        biv[j] = bi[wn0 + j * 16 + mr];
    }
#pragma unroll
    for (int i = 0; i < 4; i++) {
#pragma unroll
        for (int r = 0; r < 4; r++) {
            const int R = wm0 + i * 16 + quad * 4 + r;
            const float mean = fin[R][0] * (1.0f / 256.0f);
            const float var  = fin[R][1] * (1.0f / 256.0f) - mean * mean;
            const float rs = rsqrtf(var + LNEPS_F);
            bf16_t* crow = out + (size_t)(bm + R) * 256 + wn0 + mr;
#pragma unroll
            for (int j = 0; j < 4; j++) {
                const float v = 2.0f * (acc[i][j][r] + bcol[j]);
                crow[j * 16] = f2b((v - mean) * rs * scv[j] + biv[j]);
            }
        }
    }
}

// ---------------------------------------------------------------------------
// Wo GEMM with FUSED favor A-operand + fused LayerNorm epilogue.
// (unchanged from round 12 — already hybrid: Q from global, kvT/Wo in LDS)
// ---------------------------------------------------------------------------
__global__ __launch_bounds__(512) void gemm_favor_ln_mfma(
    const bf16_t* __restrict__ QKV, const float* __restrict__ KV,
    const bf16_t* __restrict__ WT, const float* __restrict__ bias,
    const float* __restrict__ sc, const float* __restrict__ bi,
    bf16_t* __restrict__ out)
{
    __shared__ __align__(16) bf16_t As[128 * 64];        // 16 KB
    __shared__ __align__(16) bf16_t Bs[256 * 64];        // 32 KB
    __shared__ __align__(16) bf16_t kvT[NHEAD * 34 * 36];// 19.1 KB
    __shared__ float red[8][64][2];                      // 4 KB
    __shared__ float fin[128][2];                        // 1 KB

    const int tid = threadIdx.x;
    const int wave = tid >> 6, lane = tid & 63;
    const int bm = blockIdx.x * 128;
    const int b = bm >> 12;
    const int quad = lane >> 4, mr = lane & 15;
    const int mxor = mr & 7;
    const int wm0 = (wave & 1) * 64;       // m-half
    const int wn0 = (wave >> 1) * 64;      // n-quarter

    for (int e = tid; e < NHEAD * 34 * 32; e += 512) {
        const int h = e / (34 * 32);
        const int rem = e - h * (34 * 32);
        const int d = rem >> 5, m = rem & 31;
        bf16_t v = 0;
        if (d < 33) v = f2b(KV[((size_t)(b * NHEAD + h)) * (32 * 33) + m * 33 + d]);
        kvT[(h * 34 + d) * 36 + m] = v;
    }
    __syncthreads();

    float4v acc[4][4];
#pragma unroll
    for (int i = 0; i < 4; i++)
#pragma unroll
        for (int j = 0; j < 4; j++) acc[i][j] = (float4v)(0.f);

    for (int k0 = 0; k0 < 256; k0 += 64) {
#pragma unroll
        for (int it = 0; it < 4; it++) {
            const int c = it * 512 + tid;
            const int r = c >> 3;
            const int kofs = ((c & 7) ^ (r & 7)) * 8;
            GLOAD_LDS16(WT + (size_t)r * 256 + k0 + kofs, &Bs[c * 8]);
        }
        const int h0 = k0 >> 5;
        const int Rrow = bm + wave * 16 + mr;
#pragma unroll
        for (int hh = 0; hh < 2; hh++) {
            const int h = h0 + hh;
            short8 araw = *(const short8*)(QKV + (size_t)Rrow * 768 + h * 32 + quad * 8);
            short8 a;
#pragma unroll
            for (int j = 0; j < 8; j++)
                a[j] = (short)f2b(fmaxf(b2f((bf16_t)araw[j]), 0.f) + KEPS_F);
            short8 bf0 = *(const short8*)&kvT[(h * 34 + mr) * 36 + quad * 8];
            short8 bf1 = *(const short8*)&kvT[(h * 34 + 16 + mr) * 36 + quad * 8];
            short8 bden;
#pragma unroll
            for (int j = 0; j < 8; j++) bden[j] = 0;
            if (mr == 0)
                bden = *(const short8*)&kvT[(h * 34 + 32) * 36 + quad * 8];
            float4v c0 = __builtin_amdgcn_mfma_f32_16x16x32_bf16(a, bf0, (float4v)(0.f), 0, 0, 0);
            float4v c1 = __builtin_amdgcn_mfma_f32_16x16x32_bf16(a, bf1, (float4v)(0.f), 0, 0, 0);
            float4v c2 = __builtin_amdgcn_mfma_f32_16x16x32_bf16(a, bden, (float4v)(0.f), 0, 0, 0);
#pragma unroll
            for (int r = 0; r < 4; r++) {
                const float den = __shfl(c2[r], quad << 4);
                const float rinv = 1.0f / den;
                const int R = wave * 16 + quad * 4 + r;          // local row
                const int ca = hh * 32 + mr;                     // t=0 col
                const int cbn = hh * 32 + 16 + mr;               // t=1 col
                As[(R * 8 + ((ca >> 3) ^ (R & 7))) * 8 + (ca & 7)]   = f2b(c0[r] * rinv);
                As[(R * 8 + ((cbn >> 3) ^ (R & 7))) * 8 + (cbn & 7)] = f2b(c1[r] * rinv);
            }
        }
        __syncthreads();
#pragma unroll
        for (int kk = 0; kk < 8; kk += 4) {
            short8 a[4], bfr[4];
#pragma unroll
            for (int i = 0; i < 4; i++)
                a[i] = *(const short8*)&As[((wm0 + i * 16 + mr) * 8 + ((quad + kk) ^ mxor)) * 8];
#pragma unroll
            for (int j = 0; j < 4; j++)
                bfr[j] = *(const short8*)&Bs[((wn0 + j * 16 + mr) * 8 + ((quad + kk) ^ mxor)) * 8];
#pragma unroll
            for (int i = 0; i < 4; i++)
#pragma unroll
                for (int j = 0; j < 4; j++)
                    acc[i][j] = __builtin_amdgcn_mfma_f32_16x16x32_bf16(
                        a[i], bfr[j], acc[i][j], 0, 0, 0);
        }
        __syncthreads();
    }

    float bcol[4];
#pragma unroll
    for (int j = 0; j < 4; j++) bcol[j] = bias[wn0 + j * 16 + mr];

#pragma unroll
    for (int i = 0; i < 4; i++) {
#pragma unroll
        for (int r = 0; r < 4; r++) {
            float s = 0.f, s2 = 0.f;
#pragma unroll
            for (int j = 0; j < 4; j++) {
                const float v = 2.0f * (acc[i][j][r] + bcol[j]);
                s += v; s2 += v * v;
            }
#pragma unroll
            for (int off = 1; off < 16; off <<= 1) {
                s  += __shfl_xor(s, off, 64);
                s2 += __shfl_xor(s2, off, 64);
            }
            if (mr == 0) {
                const int rl = i * 16 + quad * 4 + r;
                red[wave][rl][0] = s;
                red[wave][rl][1] = s2;
            }
        }
    }
    __syncthreads();
    if (tid < 256) {
        const int R = tid >> 1, p = tid & 1;
        const int mh = R >> 6, rl = R & 63;
        fin[R][p] = red[mh][rl][p] + red[mh + 2][rl][p]
                  + red[mh + 4][rl][p] + red[mh + 6][rl][p];
    }
    __syncthreads();

    float scv[4], biv[4];
#pragma unroll
    for (int j = 0; j < 4; j++) {
        scv[j] = sc[wn0 + j * 16 + mr];
        biv[j] = bi[wn0 + j * 16 + mr];
    }
#pragma unroll
    for (int i = 0; i < 4; i++) {
#pragma unroll
        for (int r = 0; r < 4; r++) {
            const int R = wm0 + i * 16 + quad * 4 + r;
            const float mean = fin[R][0] * (1.0f / 256.0f);
            const float var  = fin[R][1] * (1.0f / 256.0f) - mean * mean;
            const float rs = rsqrtf(var + LNEPS_F);
            bf16_t* crow = out + (size_t)(bm + R) * 256 + wn0 + mr;
#pragma unroll
            for (int j = 0; j < 4; j++) {
                const float v = 2.0f * (acc[i][j][r] + bcol[j]);
                crow[j * 16] = f2b((v - mean) * rs * scv[j] + biv[j]);
            }
        }
    }
}

// ---------------------------------------------------------------------------
// Zero the KV accumulator
// ---------------------------------------------------------------------------
__global__ __launch_bounds__(256) void zero_kv(float* __restrict__ KV)
{
    int i = blockIdx.x * 256 + threadIdx.x;
    if (i < KV_ELEMS) KV[i] = 0.f;
}

// ---------------------------------------------------------------------------
// FAVOR kv state via MFMA. Per (b,h): KV[32x33] = kp^T[32xL] @ [V|1][Lx33].
// ---------------------------------------------------------------------------
__global__ __launch_bounds__(256) void kv_mfma(
    const bf16_t* __restrict__ QKV, float* __restrict__ KV)
{
    __shared__ __align__(16) char smem[24576];
    bf16_t (*kp)[36] = (bf16_t(*)[36])smem;                 // 128x36x2 = 9216 B
    bf16_t (*vv)[52] = (bf16_t(*)[52])(smem + 9216);        // 128x52x2 = 13312 B
    float (*red)[6][64][4] = (float(*)[6][64][4])smem;      // 24576 B (aliases)

    const int bh = blockIdx.x;
    const int b = bh >> 3, h = bh & 7;
    const size_t rowbase = (size_t)b * LSEQ + blockIdx.y * 512;
    const int tid = threadIdx.x;
    const int wave = tid >> 6, lane = tid & 63;
    const int quad = lane >> 4, mr = lane & 15;

    for (int e = tid; e < 128 * 20; e += 256) {
        const int l = e / 20, c = 32 + (e % 20);
        vv[l][c] = (c == 32) ? (bf16_t)0x3F80 : (bf16_t)0;
    }

    float4v acc[2][3];
#pragma unroll
    for (int i = 0; i < 2; i++)
#pragma unroll
        for (int t = 0; t < 3; t++) acc[i][t] = (float4v)(0.f);

    for (int pass = 0; pass < 4; pass++) {
        __syncthreads();
        const size_t lp = rowbase + pass * 128;
#pragma unroll
        for (int it = 0; it < 4; it++) {
            const int e = tid + it * 256;
            const int l = e >> 3, c0 = (e & 7) * 4;
            const bf16_t* src = QKV + (lp + l) * 768 + 256 + h * 32 + c0;
            ushort4 kq = *(const ushort4*)src;
            ushort4 vq = *(const ushort4*)(src + 256);
            ushort4 ko;
            ko.x = f2b(fmaxf(b2f(kq.x), 0.f) + KEPS_F);
            ko.y = f2b(fmaxf(b2f(kq.y), 0.f) + KEPS_F);
            ko.z = f2b(fmaxf(b2f(kq.z), 0.f) + KEPS_F);
            ko.w = f2b(fmaxf(b2f(kq.w), 0.f) + KEPS_F);
            *(ushort4*)&kp[l][c0] = ko;
            *(ushort4*)&vv[l][c0] = vq;
        }
        __syncthreads();

        const int lw = wave * 32 + quad * 8;
        short8 a[2], bb[3];
#pragma unroll
        for (int i = 0; i < 2; i++)
#pragma unroll
            for (int j = 0; j < 8; j++)
                a[i][j] = (short)kp[lw + j][i * 16 + mr];
#pragma unroll
        for (int t = 0; t < 3; t++)
#pragma unroll
            for (int j = 0; j < 8; j++)
                bb[t][j] = (short)vv[lw + j][t * 16 + mr];
#pragma unroll
        for (int i = 0; i < 2; i++)
#pragma unroll
            for (int t = 0; t < 3; t++)
                acc[i][t] = __builtin_amdgcn_mfma_f32_16x16x32_bf16(
                    a[i], bb[t], acc[i][t], 0, 0, 0);
    }

    __syncthreads();
#pragma unroll
    for (int i = 0; i < 2; i++)
#pragma unroll
        for (int t = 0; t < 3; t++)
#pragma unroll
            for (int r = 0; r < 4; r++)
                red[wave][i * 3 + t][lane][r] = acc[i][t][r];
    __syncthreads();

    float* dst = KV + (size_t)bh * (32 * 33);
    for (int e = tid; e < 6 * 64 * 4; e += 256) {
        const int t = e >> 8, li = (e >> 2) & 63, r = e & 3;
        const float s = red[0][t][li][r] + red[1][t][li][r]
                      + red[2][t][li][r] + red[3][t][li][r];
        const int i = t / 3, j = t % 3;
        const int m = i * 16 + (li >> 4) * 4 + r;
        const int d = j * 16 + (li & 15);
        if (d < 33) atomicAdd(&dst[m * 33 + d], s);
    }
}

// ---------------------------------------------------------------------------
// Head (fp32 out): out[0:4096] = x[:,0,:] ; out[4096:4608] = x@qpW + qpb
// ---------------------------------------------------------------------------
__global__ __launch_bounds__(256) void head_kernel(
    const bf16_t* __restrict__ X, const float* __restrict__ qpW,
    const float* __restrict__ qpb, float* __restrict__ out)
{
    const int b = blockIdx.x, j = threadIdx.x;
    __shared__ float xr[HIDD];
    float v = b2f(X[((size_t)b * LSEQ) * HIDD + j]);
    xr[j] = v;
    out[b * HIDD + j] = v;
    __syncthreads();
    if (j < 32) {
        float acc = qpb[j];
        for (int d = 0; d < HIDD; d++)
            acc = fmaf(xr[d], qpW[d * 32 + j], acc);
        out[NB * HIDD + b * 32 + j] = acc;
    }
}

// ---------------------------------------------------------------------------
extern "C" void kernel_launch(void* const* d_in, const int* in_sizes, int n_in,
                              void* d_out, int out_size, void* d_ws, size_t ws_size,
                              hipStream_t stream)
{
    const float* hidden = (const float*)d_in[0];
    const float* ins    = (const float*)d_in[1];
    const int*   resets = (const int*)d_in[2];
    const float* embW   = (const float*)d_in[3];
    const float* embb   = (const float*)d_in[4];
    const float* Wq = (const float*)d_in[5];
    const float* bq = (const float*)d_in[6];
    const float* Wk = (const float*)d_in[7];
    const float* bk = (const float*)d_in[8];
    const float* Wv = (const float*)d_in[9];
    const float* bv = (const float*)d_in[10];
    const float* Wo = (const float*)d_in[11];
    const float* bo = (const float*)d_in[12];
    const float* ln1s = (const float*)d_in[13];
    const float* ln1b = (const float*)d_in[14];
    const float* W1 = (const float*)d_in[15];
    const float* b1 = (const float*)d_in[16];
    const float* W2 = (const float*)d_in[17];
    const float* b2 = (const float*)d_in[18];
    const float* ln2s = (const float*)d_in[19];
    const float* ln2b = (const float*)d_in[20];
    const float* qpW = (const float*)d_in[21];
    const float* qpb = (const float*)d_in[22];

    // ---- workspace (~175 MB < 256 MiB) ----
    const size_t ACT_SZ = (size_t)MROWS * HIDD;            // 16.78M elems
    bf16_t* X    = (bf16_t*)d_ws;                          // 33.5 MB
    bf16_t* QKV  = X + ACT_SZ;                             // 65536x768 = 100.7 MB
    bf16_t* H1   = QKV;                                    // alias: 65536x1024
                                                           // spans QKV + 33.5 MB spare
    bf16_t* Ain  = QKV;                                    // alias (pre-layer only)
    float*  KV   = (float*)(QKV + (size_t)MROWS * FFD);    // after H1 span
    float*  bqkv = KV + KV_ELEMS;                          // 4x768 f32
    bf16_t* WqkvT = (bf16_t*)(bqkv + NLAY * 768);          // [l][768][256]
    bf16_t* WoT   = WqkvT + (size_t)NLAY * 3 * HIDD * HIDD;
    bf16_t* W1T   = WoT + (size_t)NLAY * HIDD * HIDD;
    bf16_t* W2T   = W1T + (size_t)NLAY * HIDD * FFD;
    bf16_t* embWT = W2T + (size_t)NLAY * FFD * HIDD;

    const dim3 blk(256);
    const dim3 blk512(512);
    const size_t HH = (size_t)HIDD * HIDD;

    conv_transpose_kernel<<<dim3(8, 8, NLAY), blk, 0, stream>>>(Wq, WqkvT,          HIDD, HIDD, HH, 3 * HH);
    conv_transpose_kernel<<<dim3(8, 8, NLAY), blk, 0, stream>>>(Wk, WqkvT + HH,     HIDD, HIDD, HH, 3 * HH);
    conv_transpose_kernel<<<dim3(8, 8, NLAY), blk, 0, stream>>>(Wv, WqkvT + 2 * HH, HIDD, HIDD, HH, 3 * HH);
    conv_transpose_kernel<<<dim3(8, 8, NLAY), blk, 0, stream>>>(Wo, WoT, HIDD, HIDD, HH, HH);
    conv_transpose_kernel<<<dim3(32, 8, NLAY), blk, 0, stream>>>(W1, W1T, HIDD, FFD, (size_t)HIDD * FFD, (size_t)HIDD * FFD);
    conv_transpose_kernel<<<dim3(8, 32, NLAY), blk, 0, stream>>>(W2, W2T, FFD, HIDD, (size_t)HIDD * FFD, (size_t)HIDD * FFD);
    conv_transpose_kernel<<<dim3(8, 4, 1), blk, 0, stream>>>(embW, embWT, 128, HIDD, 0, 0);
    concat_bias_kernel<<<NLAY, blk, 0, stream>>>(bq, bk, bv, bqkv);

    prep_a_kernel<<<MROWS / 2, blk, 0, stream>>>(ins, Ain);
    gemm_mfma<0><<<dim3(1, 512), blk512, 0, stream>>>(Ain, embWT, embb, X, MROWS, HIDD, 128, 128, HIDD);
    fix_row0_kernel<<<NB, blk, 0, stream>>>(hidden, resets, X);

    for (int l = 0; l < NLAY; l++) {
        // fused QKV projection: X[M][256] @ Wqkv[256][768] -> QKV[M][768]
        gemm_mfma<0><<<dim3(3, 512), blk512, 0, stream>>>(X, WqkvT + (size_t)l * 3 * HH,
                                                          bqkv + l * 768, QKV, MROWS, 768, HIDD, HIDD, 768);

        zero_kv<<<(KV_ELEMS + 255) / 256, blk, 0, stream>>>(KV);
        kv_mfma<<<dim3(NB * NHEAD, 8), blk, 0, stream>>>(QKV, KV);

        // favor + Wo + residual-doubling + LN1 fused -> X
        gemm_favor_ln_mfma<<<MROWS / 128, blk512, 0, stream>>>(
            QKV, KV, WoT + (size_t)l * HH, bo + l * HIDD,
            ln1s + l * HIDD, ln1b + l * HIDD, X);

        // FF1 (single dispatch): X @ W1 -> H1 (over dead QKV region + spare)
        gemm_mfma<1><<<dim3(4, 512), blk512, 0, stream>>>(X, W1T + (size_t)l * HIDD * FFD,
                                                          b1 + l * FFD, H1, MROWS, FFD, HIDD, HIDD, FFD);
        // FF2 + residual-doubling + LN2 fused -> X (single dispatch)
        gemm_ln_mfma<<<MROWS / 128, blk512, 0, stream>>>(
            H1, W2T + (size_t)l * FFD * HIDD, b2 + l * HIDD,
            ln2s + l * HIDD, ln2b + l * HIDD, X, FFD, FFD);
    }

    head_kernel<<<NB, blk, 0, stream>>>(X, qpW, qpb, (float*)d_out);
}

// Round 14
// 1005.823 us; speedup vs baseline: 1.6235x; 1.6235x over previous
//
#include <hip/hip_runtime.h>

// ---------------------------------------------------------------------------
// TransformerAgent (Performer/FAVOR+ encoder), MI355X gfx950.
// Round 14: revert round-13 hybrid (regressed: exposed per-wave HBM latency).
// = round-12 structure (1024us) + XCD-aware 1-D grid swizzle in gemm_mfma:
// all n-blocks of an m-block land consecutively on ONE XCD so the A-tile is
// HBM-fetched once and L2-served (r12 FETCH was 2x ideal: 67MB vs 34MB).
// B=16, L=4096(=1+4095), HID=256, NH=8, DH=32, FF=1024, NL=4, ACT=32
// ---------------------------------------------------------------------------

typedef unsigned short bf16_t;
typedef __attribute__((ext_vector_type(8))) short short8;
typedef __attribute__((ext_vector_type(4))) float float4v;

#define NB 16
#define LSEQ 4096
#define MROWS (NB * LSEQ)      // 65536
#define HIDD 256
#define NHEAD 8
#define DHEAD 32
#define FFD 1024
#define NLAY 4
#define KEPS_F 1e-3f
#define LNEPS_F 1e-6f
#define KV_ELEMS (NB * NHEAD * 32 * 33)   // 135168

__device__ __forceinline__ float b2f(bf16_t h) {
    return __uint_as_float(((unsigned int)h) << 16);
}
__device__ __forceinline__ bf16_t f2b(float f) {
    unsigned int u = __float_as_uint(f);
    u += 0x7fffu + ((u >> 16) & 1u);   // round-to-nearest-even
    return (bf16_t)(u >> 16);
}

// async global->LDS, 16B per lane
#define GLOAD_LDS16(g, l)                                                     \
    __builtin_amdgcn_global_load_lds(                                         \
        (const __attribute__((address_space(1))) void*)(g),                   \
        (__attribute__((address_space(3))) void*)(l), 16, 0, 0)

// ---------------------------------------------------------------------------
// Convert+transpose: in[z*ils + R][C] f32 -> out[z*ols + C][R] bf16.
// ---------------------------------------------------------------------------
__global__ __launch_bounds__(256) void conv_transpose_kernel(
    const float* __restrict__ in, bf16_t* __restrict__ out, int R, int C,
    size_t ils, size_t ols)
{
    __shared__ float tile[32][33];
    const size_t ib = (size_t)blockIdx.z * ils;
    const size_t ob = (size_t)blockIdx.z * ols;
    const int r0 = blockIdx.y * 32, c0 = blockIdx.x * 32;
    const int tx = threadIdx.x & 31, ty = threadIdx.x >> 5;   // 32 x 8
#pragma unroll
    for (int rr = ty; rr < 32; rr += 8)
        tile[rr][tx] = in[ib + (size_t)(r0 + rr) * C + c0 + tx];
    __syncthreads();
#pragma unroll
    for (int rr = ty; rr < 32; rr += 8)
        out[ob + (size_t)(c0 + rr) * R + r0 + tx] = f2b(tile[tx][rr]);
}

// concat per-layer q/k/v biases into bqkv[l][768]
__global__ __launch_bounds__(256) void concat_bias_kernel(
    const float* __restrict__ bq, const float* __restrict__ bk,
    const float* __restrict__ bv, float* __restrict__ bqkv)
{
    const int l = blockIdx.x, j = threadIdx.x;
    bqkv[l * 768 + j]       = bq[l * 256 + j];
    bqkv[l * 768 + 256 + j] = bk[l * 256 + j];
    bqkv[l * 768 + 512 + j] = bv[l * 256 + j];
}

// ---------------------------------------------------------------------------
// Embed A-prep: Ain[b*4096+l][128] = (l==0) ? 0 : bf16(ins[b][l-1][:])
// ---------------------------------------------------------------------------
__global__ __launch_bounds__(256) void prep_a_kernel(
    const float* __restrict__ ins, bf16_t* __restrict__ Ain)
{
    const int row = blockIdx.x * 2 + (threadIdx.x >> 7);
    const int j = threadIdx.x & 127;
    const int b = row >> 12, l = row & (LSEQ - 1);
    bf16_t v = 0;
    if (l != 0) v = f2b(ins[((size_t)b * 4095 + (l - 1)) * 128 + j]);
    Ain[(size_t)row * 128 + j] = v;
}

// X[b,0,:] = resets ? 0 : hidden
__global__ __launch_bounds__(256) void fix_row0_kernel(
    const float* __restrict__ hidden, const int* __restrict__ resets,
    bf16_t* __restrict__ X)
{
    const int b = blockIdx.x, j = threadIdx.x;
    float v = resets[b] ? 0.f : hidden[b * HIDD + j];
    X[((size_t)b * LSEQ) * HIDD + j] = f2b(v);
}

// ---------------------------------------------------------------------------
// MFMA GEMM (plain): C = act(A @ W + bias); WT[N][K]. 512 thr = 8 waves,
// block 128x256, wave 64x64 (2m x 4n). XOR-swizzled LDS.
// 1-D grid with XCD-aware decode: all n-blocks of one m-block are
// consecutive slots on one XCD (id%8) -> A-tile fetched once, L2-served.
// Requires M/128 % 8 == 0.
// ---------------------------------------------------------------------------
template <int MODE>
__global__ __launch_bounds__(512) void gemm_mfma(
    const bf16_t* __restrict__ A, const bf16_t* __restrict__ WT,
    const float* __restrict__ bias, bf16_t* __restrict__ C,
    int M, int N, int K, int lda, int ldc)
{
    __shared__ __align__(16) bf16_t As[128 * 64];   // 16 KB
    __shared__ __align__(16) bf16_t Bs[256 * 64];   // 32 KB
    const int tid = threadIdx.x;
    const int wave = tid >> 6, lane = tid & 63;

    // XCD-aware decode (identity when N==256)
    const int Nn = N >> 8;
    const int id = blockIdx.x;
    const int s = id >> 3;
    const int bm = ((id & 7) + ((s / Nn) << 3)) * 128;
    const int bn = (s % Nn) * 256;

    const int quad = lane >> 4, mr = lane & 15;
    const int mxor = mr & 7;
    const int wm0 = (wave & 1) * 64;       // m-half
    const int wn0 = (wave >> 1) * 64;      // n-quarter

    float4v acc[4][4];
#pragma unroll
    for (int i = 0; i < 4; i++)
#pragma unroll
        for (int j = 0; j < 4; j++) acc[i][j] = (float4v)(0.f);

    for (int k0 = 0; k0 < K; k0 += 64) {
#pragma unroll
        for (int it = 0; it < 2; it++) {            // A: 1024 chunks
            const int c = it * 512 + tid;
            const int r = c >> 3;
            const int kofs = ((c & 7) ^ (r & 7)) * 8;
            GLOAD_LDS16(A + (size_t)(bm + r) * lda + k0 + kofs, &As[c * 8]);
        }
#pragma unroll
        for (int it = 0; it < 4; it++) {            // B: 2048 chunks
            const int c = it * 512 + tid;
            const int r = c >> 3;
            const int kofs = ((c & 7) ^ (r & 7)) * 8;
            GLOAD_LDS16(WT + (size_t)(bn + r) * K + k0 + kofs, &Bs[c * 8]);
        }
        __syncthreads();
#pragma unroll
        for (int kk = 0; kk < 8; kk += 4) {
            short8 a[4], b[4];
#pragma unroll
            for (int i = 0; i < 4; i++)
                a[i] = *(const short8*)&As[((wm0 + i * 16 + mr) * 8 + ((quad + kk) ^ mxor)) * 8];
#pragma unroll
            for (int j = 0; j < 4; j++)
                b[j] = *(const short8*)&Bs[((wn0 + j * 16 + mr) * 8 + ((quad + kk) ^ mxor)) * 8];
#pragma unroll
            for (int i = 0; i < 4; i++)
#pragma unroll
                for (int j = 0; j < 4; j++)
                    acc[i][j] = __builtin_amdgcn_mfma_f32_16x16x32_bf16(
                        a[i], b[j], acc[i][j], 0, 0, 0);
        }
        __syncthreads();
    }

    float bcol[4];
#pragma unroll
    for (int j = 0; j < 4; j++) bcol[j] = bias[bn + wn0 + j * 16 + mr];
#pragma unroll
    for (int i = 0; i < 4; i++) {
#pragma unroll
        for (int r = 0; r < 4; r++) {
            const int grow = bm + wm0 + i * 16 + quad * 4 + r;
            bf16_t* crow = C + (size_t)grow * ldc + bn + wn0 + mr;
#pragma unroll
            for (int j = 0; j < 4; j++) {
                float v = acc[i][j][r] + bcol[j];
                if (MODE == 1) v = fmaxf(v, 0.f);
                crow[j * 16] = f2b(v);
            }
        }
    }
}

// ---------------------------------------------------------------------------
// MFMA GEMM + fused LayerNorm epilogue (round-9/11/12 proven version).
// out = LN(2*(A@W + bias)) * sc + bi. N=256; 512 thr = 8 waves (2m x 4n).
// ---------------------------------------------------------------------------
__global__ __launch_bounds__(512) void gemm_ln_mfma(
    const bf16_t* __restrict__ A, const bf16_t* __restrict__ WT,
    const float* __restrict__ bias, const float* __restrict__ sc,
    const float* __restrict__ bi, bf16_t* __restrict__ out,
    int K, int lda)
{
    __shared__ __align__(16) bf16_t As[128 * 64];   // 16 KB
    __shared__ __align__(16) bf16_t Bs[256 * 64];   // 32 KB
    __shared__ float red[8][64][2];                 // 4 KB
    __shared__ float fin[128][2];                   // 1 KB

    const int tid = threadIdx.x;
    const int wave = tid >> 6, lane = tid & 63;
    const int bm = blockIdx.x * 128;
    const int quad = lane >> 4, mr = lane & 15;
    const int mxor = mr & 7;
    const int wm0 = (wave & 1) * 64;       // m-half
    const int wn0 = (wave >> 1) * 64;      // n-quarter

    float4v acc[4][4];
#pragma unroll
    for (int i = 0; i < 4; i++)
#pragma unroll
        for (int j = 0; j < 4; j++) acc[i][j] = (float4v)(0.f);

    for (int k0 = 0; k0 < K; k0 += 64) {
#pragma unroll
        for (int it = 0; it < 6; it++) {
            const int c = it * 512 + tid;           // 0..3071 (wave-uniform branch)
            if (c < 1024) {
                const int r = c >> 3;
                const int kofs = ((c & 7) ^ (r & 7)) * 8;
                GLOAD_LDS16(A + (size_t)(bm + r) * lda + k0 + kofs, &As[c * 8]);
            } else {
                const int cb = c - 1024;
                const int r = cb >> 3;
                const int kofs = ((cb & 7) ^ (r & 7)) * 8;
                GLOAD_LDS16(WT + (size_t)r * K + k0 + kofs, &Bs[cb * 8]);
            }
        }
        __syncthreads();
#pragma unroll
        for (int kk = 0; kk < 8; kk += 4) {
            short8 a[4], b[4];
#pragma unroll
            for (int i = 0; i < 4; i++)
                a[i] = *(const short8*)&As[((wm0 + i * 16 + mr) * 8 + ((quad + kk) ^ mxor)) * 8];
#pragma unroll
            for (int j = 0; j < 4; j++)
                b[j] = *(const short8*)&Bs[((wn0 + j * 16 + mr) * 8 + ((quad + kk) ^ mxor)) * 8];
#pragma unroll
            for (int i = 0; i < 4; i++)
#pragma unroll
                for (int j = 0; j < 4; j++)
                    acc[i][j] = __builtin_amdgcn_mfma_f32_16x16x32_bf16(
                        a[i], b[j], acc[i][j], 0, 0, 0);
        }
        __syncthreads();
    }

    float bcol[4];
#pragma unroll
    for (int j = 0; j < 4; j++) bcol[j] = bias[wn0 + j * 16 + mr];

#pragma unroll
    for (int i = 0; i < 4; i++) {
#pragma unroll
        for (int r = 0; r < 4; r++) {
            float s = 0.f, s2 = 0.f;
#pragma unroll
            for (int j = 0; j < 4; j++) {
                const float v = 2.0f * (acc[i][j][r] + bcol[j]);
                s += v; s2 += v * v;
            }
#pragma unroll
            for (int off = 1; off < 16; off <<= 1) {
                s  += __shfl_xor(s, off, 64);
                s2 += __shfl_xor(s2, off, 64);
            }
            if (mr == 0) {
                const int rl = i * 16 + quad * 4 + r;
                red[wave][rl][0] = s;
                red[wave][rl][1] = s2;
            }
        }
    }
    __syncthreads();
    if (tid < 256) {
        const int R = tid >> 1, p = tid & 1;
        const int mh = R >> 6, rl = R & 63;
        fin[R][p] = red[mh][rl][p] + red[mh + 2][rl][p]
                  + red[mh + 4][rl][p] + red[mh + 6][rl][p];
    }
    __syncthreads();

    float scv[4], biv[4];
#pragma unroll
    for (int j = 0; j < 4; j++) {
        scv[j] = sc[wn0 + j * 16 + mr];
        biv[j] = bi[wn0 + j * 16 + mr];
    }
#pragma unroll
    for (int i = 0; i < 4; i++) {
#pragma unroll
        for (int r = 0; r < 4; r++) {
            const int R = wm0 + i * 16 + quad * 4 + r;
            const float mean = fin[R][0] * (1.0f / 256.0f);
            const float var  = fin[R][1] * (1.0f / 256.0f) - mean * mean;
            const float rs = rsqrtf(var + LNEPS_F);
            bf16_t* crow = out + (size_t)(bm + R) * 256 + wn0 + mr;
#pragma unroll
            for (int j = 0; j < 4; j++) {
                const float v = 2.0f * (acc[i][j][r] + bcol[j]);
                crow[j * 16] = f2b((v - mean) * rs * scv[j] + biv[j]);
            }
        }
    }
}

// ---------------------------------------------------------------------------
// Wo GEMM with FUSED favor A-operand + fused LayerNorm epilogue.
// (round-12 proven version)
// ---------------------------------------------------------------------------
__global__ __launch_bounds__(512) void gemm_favor_ln_mfma(
    const bf16_t* __restrict__ QKV, const float* __restrict__ KV,
    const bf16_t* __restrict__ WT, const float* __restrict__ bias,
    const float* __restrict__ sc, const float* __restrict__ bi,
    bf16_t* __restrict__ out)
{
    __shared__ __align__(16) bf16_t As[128 * 64];        // 16 KB
    __shared__ __align__(16) bf16_t Bs[256 * 64];        // 32 KB
    __shared__ __align__(16) bf16_t kvT[NHEAD * 34 * 36];// 19.1 KB
    __shared__ float red[8][64][2];                      // 4 KB
    __shared__ float fin[128][2];                        // 1 KB

    const int tid = threadIdx.x;
    const int wave = tid >> 6, lane = tid & 63;
    const int bm = blockIdx.x * 128;
    const int b = bm >> 12;
    const int quad = lane >> 4, mr = lane & 15;
    const int mxor = mr & 7;
    const int wm0 = (wave & 1) * 64;       // m-half
    const int wn0 = (wave >> 1) * 64;      // n-quarter

    for (int e = tid; e < NHEAD * 34 * 32; e += 512) {
        const int h = e / (34 * 32);
        const int rem = e - h * (34 * 32);
        const int d = rem >> 5, m = rem & 31;
        bf16_t v = 0;
        if (d < 33) v = f2b(KV[((size_t)(b * NHEAD + h)) * (32 * 33) + m * 33 + d]);
        kvT[(h * 34 + d) * 36 + m] = v;
    }
    __syncthreads();

    float4v acc[4][4];
#pragma unroll
    for (int i = 0; i < 4; i++)
#pragma unroll
        for (int j = 0; j < 4; j++) acc[i][j] = (float4v)(0.f);

    for (int k0 = 0; k0 < 256; k0 += 64) {
#pragma unroll
        for (int it = 0; it < 4; it++) {
            const int c = it * 512 + tid;
            const int r = c >> 3;
            const int kofs = ((c & 7) ^ (r & 7)) * 8;
            GLOAD_LDS16(WT + (size_t)r * 256 + k0 + kofs, &Bs[c * 8]);
        }
        const int h0 = k0 >> 5;
        const int Rrow = bm + wave * 16 + mr;
#pragma unroll
        for (int hh = 0; hh < 2; hh++) {
            const int h = h0 + hh;
            short8 araw = *(const short8*)(QKV + (size_t)Rrow * 768 + h * 32 + quad * 8);
            short8 a;
#pragma unroll
            for (int j = 0; j < 8; j++)
                a[j] = (short)f2b(fmaxf(b2f((bf16_t)araw[j]), 0.f) + KEPS_F);
            short8 bf0 = *(const short8*)&kvT[(h * 34 + mr) * 36 + quad * 8];
            short8 bf1 = *(const short8*)&kvT[(h * 34 + 16 + mr) * 36 + quad * 8];
            short8 bden;
#pragma unroll
            for (int j = 0; j < 8; j++) bden[j] = 0;
            if (mr == 0)
                bden = *(const short8*)&kvT[(h * 34 + 32) * 36 + quad * 8];
            float4v c0 = __builtin_amdgcn_mfma_f32_16x16x32_bf16(a, bf0, (float4v)(0.f), 0, 0, 0);
            float4v c1 = __builtin_amdgcn_mfma_f32_16x16x32_bf16(a, bf1, (float4v)(0.f), 0, 0, 0);
            float4v c2 = __builtin_amdgcn_mfma_f32_16x16x32_bf16(a, bden, (float4v)(0.f), 0, 0, 0);
#pragma unroll
            for (int r = 0; r < 4; r++) {
                const float den = __shfl(c2[r], quad << 4);
                const float rinv = 1.0f / den;
                const int R = wave * 16 + quad * 4 + r;          // local row
                const int ca = hh * 32 + mr;                     // t=0 col
                const int cbn = hh * 32 + 16 + mr;               // t=1 col
                As[(R * 8 + ((ca >> 3) ^ (R & 7))) * 8 + (ca & 7)]   = f2b(c0[r] * rinv);
                As[(R * 8 + ((cbn >> 3) ^ (R & 7))) * 8 + (cbn & 7)] = f2b(c1[r] * rinv);
            }
        }
        __syncthreads();
#pragma unroll
        for (int kk = 0; kk < 8; kk += 4) {
            short8 a[4], bfr[4];
#pragma unroll
            for (int i = 0; i < 4; i++)
                a[i] = *(const short8*)&As[((wm0 + i * 16 + mr) * 8 + ((quad + kk) ^ mxor)) * 8];
#pragma unroll
            for (int j = 0; j < 4; j++)
                bfr[j] = *(const short8*)&Bs[((wn0 + j * 16 + mr) * 8 + ((quad + kk) ^ mxor)) * 8];
#pragma unroll
            for (int i = 0; i < 4; i++)
#pragma unroll
                for (int j = 0; j < 4; j++)
                    acc[i][j] = __builtin_amdgcn_mfma_f32_16x16x32_bf16(
                        a[i], bfr[j], acc[i][j], 0, 0, 0);
        }
        __syncthreads();
    }

    float bcol[4];
#pragma unroll
    for (int j = 0; j < 4; j++) bcol[j] = bias[wn0 + j * 16 + mr];

#pragma unroll
    for (int i = 0; i < 4; i++) {
#pragma unroll
        for (int r = 0; r < 4; r++) {
            float s = 0.f, s2 = 0.f;
#pragma unroll
            for (int j = 0; j < 4; j++) {
                const float v = 2.0f * (acc[i][j][r] + bcol[j]);
                s += v; s2 += v * v;
            }
#pragma unroll
            for (int off = 1; off < 16; off <<= 1) {
                s  += __shfl_xor(s, off, 64);
                s2 += __shfl_xor(s2, off, 64);
            }
            if (mr == 0) {
                const int rl = i * 16 + quad * 4 + r;
                red[wave][rl][0] = s;
                red[wave][rl][1] = s2;
            }
        }
    }
    __syncthreads();
    if (tid < 256) {
        const int R = tid >> 1, p = tid & 1;
        const int mh = R >> 6, rl = R & 63;
        fin[R][p] = red[mh][rl][p] + red[mh + 2][rl][p]
                  + red[mh + 4][rl][p] + red[mh + 6][rl][p];
    }
    __syncthreads();

    float scv[4], biv[4];
#pragma unroll
    for (int j = 0; j < 4; j++) {
        scv[j] = sc[wn0 + j * 16 + mr];
        biv[j] = bi[wn0 + j * 16 + mr];
    }
#pragma unroll
    for (int i = 0; i < 4; i++) {
#pragma unroll
        for (int r = 0; r < 4; r++) {
            const int R = wm0 + i * 16 + quad * 4 + r;
            const float mean = fin[R][0] * (1.0f / 256.0f);
            const float var  = fin[R][1] * (1.0f / 256.0f) - mean * mean;
            const float rs = rsqrtf(var + LNEPS_F);
            bf16_t* crow = out + (size_t)(bm + R) * 256 + wn0 + mr;
#pragma unroll
            for (int j = 0; j < 4; j++) {
                const float v = 2.0f * (acc[i][j][r] + bcol[j]);
                crow[j * 16] = f2b((v - mean) * rs * scv[j] + biv[j]);
            }
        }
    }
}

// ---------------------------------------------------------------------------
// Zero the KV accumulator
// ---------------------------------------------------------------------------
__global__ __launch_bounds__(256) void zero_kv(float* __restrict__ KV)
{
    int i = blockIdx.x * 256 + threadIdx.x;
    if (i < KV_ELEMS) KV[i] = 0.f;
}

// ---------------------------------------------------------------------------
// FAVOR kv state via MFMA. Per (b,h): KV[32x33] = kp^T[32xL] @ [V|1][Lx33].
// ---------------------------------------------------------------------------
__global__ __launch_bounds__(256) void kv_mfma(
    const bf16_t* __restrict__ QKV, float* __restrict__ KV)
{
    __shared__ __align__(16) char smem[24576];
    bf16_t (*kp)[36] = (bf16_t(*)[36])smem;                 // 128x36x2 = 9216 B
    bf16_t (*vv)[52] = (bf16_t(*)[52])(smem + 9216);        // 128x52x2 = 13312 B
    float (*red)[6][64][4] = (float(*)[6][64][4])smem;      // 24576 B (aliases)

    const int bh = blockIdx.x;
    const int b = bh >> 3, h = bh & 7;
    const size_t rowbase = (size_t)b * LSEQ + blockIdx.y * 512;
    const int tid = threadIdx.x;
    const int wave = tid >> 6, lane = tid & 63;
    const int quad = lane >> 4, mr = lane & 15;

    for (int e = tid; e < 128 * 20; e += 256) {
        const int l = e / 20, c = 32 + (e % 20);
        vv[l][c] = (c == 32) ? (bf16_t)0x3F80 : (bf16_t)0;
    }

    float4v acc[2][3];
#pragma unroll
    for (int i = 0; i < 2; i++)
#pragma unroll
        for (int t = 0; t < 3; t++) acc[i][t] = (float4v)(0.f);

    for (int pass = 0; pass < 4; pass++) {
        __syncthreads();
        const size_t lp = rowbase + pass * 128;
#pragma unroll
        for (int it = 0; it < 4; it++) {
            const int e = tid + it * 256;
            const int l = e >> 3, c0 = (e & 7) * 4;
            const bf16_t* src = QKV + (lp + l) * 768 + 256 + h * 32 + c0;
            ushort4 kq = *(const ushort4*)src;
            ushort4 vq = *(const ushort4*)(src + 256);
            ushort4 ko;
            ko.x = f2b(fmaxf(b2f(kq.x), 0.f) + KEPS_F);
            ko.y = f2b(fmaxf(b2f(kq.y), 0.f) + KEPS_F);
            ko.z = f2b(fmaxf(b2f(kq.z), 0.f) + KEPS_F);
            ko.w = f2b(fmaxf(b2f(kq.w), 0.f) + KEPS_F);
            *(ushort4*)&kp[l][c0] = ko;
            *(ushort4*)&vv[l][c0] = vq;
        }
        __syncthreads();

        const int lw = wave * 32 + quad * 8;
        short8 a[2], bb[3];
#pragma unroll
        for (int i = 0; i < 2; i++)
#pragma unroll
            for (int j = 0; j < 8; j++)
                a[i][j] = (short)kp[lw + j][i * 16 + mr];
#pragma unroll
        for (int t = 0; t < 3; t++)
#pragma unroll
            for (int j = 0; j < 8; j++)
                bb[t][j] = (short)vv[lw + j][t * 16 + mr];
#pragma unroll
        for (int i = 0; i < 2; i++)
#pragma unroll
            for (int t = 0; t < 3; t++)
                acc[i][t] = __builtin_amdgcn_mfma_f32_16x16x32_bf16(
                    a[i], bb[t], acc[i][t], 0, 0, 0);
    }

    __syncthreads();
#pragma unroll
    for (int i = 0; i < 2; i++)
#pragma unroll
        for (int t = 0; t < 3; t++)
#pragma unroll
            for (int r = 0; r < 4; r++)
                red[wave][i * 3 + t][lane][r] = acc[i][t][r];
    __syncthreads();

    float* dst = KV + (size_t)bh * (32 * 33);
    for (int e = tid; e < 6 * 64 * 4; e += 256) {
        const int t = e >> 8, li = (e >> 2) & 63, r = e & 3;
        const float s = red[0][t][li][r] + red[1][t][li][r]
                      + red[2][t][li][r] + red[3][t][li][r];
        const int i = t / 3, j = t % 3;
        const int m = i * 16 + (li >> 4) * 4 + r;
        const int d = j * 16 + (li & 15);
        if (d < 33) atomicAdd(&dst[m * 33 + d], s);
    }
}

// ---------------------------------------------------------------------------
// Head (fp32 out): out[0:4096] = x[:,0,:] ; out[4096:4608] = x@qpW + qpb
// ---------------------------------------------------------------------------
__global__ __launch_bounds__(256) void head_kernel(
    const bf16_t* __restrict__ X, const float* __restrict__ qpW,
    const float* __restrict__ qpb, float* __restrict__ out)
{
    const int b = blockIdx.x, j = threadIdx.x;
    __shared__ float xr[HIDD];
    float v = b2f(X[((size_t)b * LSEQ) * HIDD + j]);
    xr[j] = v;
    out[b * HIDD + j] = v;
    __syncthreads();
    if (j < 32) {
        float acc = qpb[j];
        for (int d = 0; d < HIDD; d++)
            acc = fmaf(xr[d], qpW[d * 32 + j], acc);
        out[NB * HIDD + b * 32 + j] = acc;
    }
}

// ---------------------------------------------------------------------------
extern "C" void kernel_launch(void* const* d_in, const int* in_sizes, int n_in,
                              void* d_out, int out_size, void* d_ws, size_t ws_size,
                              hipStream_t stream)
{
    const float* hidden = (const float*)d_in[0];
    const float* ins    = (const float*)d_in[1];
    const int*   resets = (const int*)d_in[2];
    const float* embW   = (const float*)d_in[3];
    const float* embb   = (const float*)d_in[4];
    const float* Wq = (const float*)d_in[5];
    const float* bq = (const float*)d_in[6];
    const float* Wk = (const float*)d_in[7];
    const float* bk = (const float*)d_in[8];
    const float* Wv = (const float*)d_in[9];
    const float* bv = (const float*)d_in[10];
    const float* Wo = (const float*)d_in[11];
    const float* bo = (const float*)d_in[12];
    const float* ln1s = (const float*)d_in[13];
    const float* ln1b = (const float*)d_in[14];
    const float* W1 = (const float*)d_in[15];
    const float* b1 = (const float*)d_in[16];
    const float* W2 = (const float*)d_in[17];
    const float* b2 = (const float*)d_in[18];
    const float* ln2s = (const float*)d_in[19];
    const float* ln2b = (const float*)d_in[20];
    const float* qpW = (const float*)d_in[21];
    const float* qpb = (const float*)d_in[22];

    // ---- workspace (~175 MB < 256 MiB) ----
    const size_t ACT_SZ = (size_t)MROWS * HIDD;            // 16.78M elems
    bf16_t* X    = (bf16_t*)d_ws;                          // 33.5 MB
    bf16_t* QKV  = X + ACT_SZ;                             // 65536x768 = 100.7 MB
    bf16_t* H1   = QKV;                                    // alias: 65536x1024
                                                           // spans QKV + 33.5 MB spare
    bf16_t* Ain  = QKV;                                    // alias (pre-layer only)
    float*  KV   = (float*)(QKV + (size_t)MROWS * FFD);    // after H1 span
    float*  bqkv = KV + KV_ELEMS;                          // 4x768 f32
    bf16_t* WqkvT = (bf16_t*)(bqkv + NLAY * 768);          // [l][768][256]
    bf16_t* WoT   = WqkvT + (size_t)NLAY * 3 * HIDD * HIDD;
    bf16_t* W1T   = WoT + (size_t)NLAY * HIDD * HIDD;
    bf16_t* W2T   = W1T + (size_t)NLAY * HIDD * FFD;
    bf16_t* embWT = W2T + (size_t)NLAY * FFD * HIDD;

    const dim3 blk(256);
    const dim3 blk512(512);
    const size_t HH = (size_t)HIDD * HIDD;

    conv_transpose_kernel<<<dim3(8, 8, NLAY), blk, 0, stream>>>(Wq, WqkvT,          HIDD, HIDD, HH, 3 * HH);
    conv_transpose_kernel<<<dim3(8, 8, NLAY), blk, 0, stream>>>(Wk, WqkvT + HH,     HIDD, HIDD, HH, 3 * HH);
    conv_transpose_kernel<<<dim3(8, 8, NLAY), blk, 0, stream>>>(Wv, WqkvT + 2 * HH, HIDD, HIDD, HH, 3 * HH);
    conv_transpose_kernel<<<dim3(8, 8, NLAY), blk, 0, stream>>>(Wo, WoT, HIDD, HIDD, HH, HH);
    conv_transpose_kernel<<<dim3(32, 8, NLAY), blk, 0, stream>>>(W1, W1T, HIDD, FFD, (size_t)HIDD * FFD, (size_t)HIDD * FFD);
    conv_transpose_kernel<<<dim3(8, 32, NLAY), blk, 0, stream>>>(W2, W2T, FFD, HIDD, (size_t)HIDD * FFD, (size_t)HIDD * FFD);
    conv_transpose_kernel<<<dim3(8, 4, 1), blk, 0, stream>>>(embW, embWT, 128, HIDD, 0, 0);
    concat_bias_kernel<<<NLAY, blk, 0, stream>>>(bq, bk, bv, bqkv);

    prep_a_kernel<<<MROWS / 2, blk, 0, stream>>>(ins, Ain);
    gemm_mfma<0><<<dim3(512), blk512, 0, stream>>>(Ain, embWT, embb, X, MROWS, HIDD, 128, 128, HIDD);
    fix_row0_kernel<<<NB, blk, 0, stream>>>(hidden, resets, X);

    for (int l = 0; l < NLAY; l++) {
        // fused QKV projection: X[M][256] @ Wqkv[256][768] -> QKV[M][768]
        gemm_mfma<0><<<dim3(512 * 3), blk512, 0, stream>>>(X, WqkvT + (size_t)l * 3 * HH,
                                                           bqkv + l * 768, QKV, MROWS, 768, HIDD, HIDD, 768);

        zero_kv<<<(KV_ELEMS + 255) / 256, blk, 0, stream>>>(KV);
        kv_mfma<<<dim3(NB * NHEAD, 8), blk, 0, stream>>>(QKV, KV);

        // favor + Wo + residual-doubling + LN1 fused -> X
        gemm_favor_ln_mfma<<<MROWS / 128, blk512, 0, stream>>>(
            QKV, KV, WoT + (size_t)l * HH, bo + l * HIDD,
            ln1s + l * HIDD, ln1b + l * HIDD, X);

        // FF1 (single dispatch): X @ W1 -> H1 (over dead QKV region + spare)
        gemm_mfma<1><<<dim3(512 * 4), blk512, 0, stream>>>(X, W1T + (size_t)l * HIDD * FFD,
                                                           b1 + l * FFD, H1, MROWS, FFD, HIDD, HIDD, FFD);
        // FF2 + residual-doubling + LN2 fused -> X (single dispatch)
        gemm_ln_mfma<<<MROWS / 128, blk512, 0, stream>>>(
            H1, W2T + (size_t)l * FFD * HIDD, b2 + l * HIDD,
            ln2s + l * HIDD, ln2b + l * HIDD, X, FFD, FFD);
    }

    head_kernel<<<NB, blk, 0, stream>>>(X, qpW, qpb, (float*)d_out);
}